// Round 3
// baseline (674.114 us; speedup 1.0000x reference)
//
#include <hip/hip_runtime.h>
#include <hip/hip_bf16.h>

#define N_NODES 50000
#define N_EDGES 600000
#define N_GRAPHS 256
#define C 128

// ---------------------------------------------------------------- degree histogram
__global__ void k_deg(const int* __restrict__ tgt, int* __restrict__ deg) {
    int e = blockIdx.x * blockDim.x + threadIdx.x;
    if (e < N_EDGES) atomicAdd(&deg[tgt[e]], 1);
}

__global__ void k_deginv(const int* __restrict__ deg, float* __restrict__ dinv) {
    int n = blockIdx.x * blockDim.x + threadIdx.x;
    if (n >= N_NODES) return;
    dinv[n] = 1.0f / fmaxf((float)deg[n], 1.0f);
}

// ---------------------------------------------------------------- exclusive scan of deg -> rowptr
// thread-coarsened: 1024 threads x 49 elems; seq sum -> wave-shuffle block scan -> seq writeback.
// 2 barriers total (vs ~980 in the old Hillis-Steele version).
#define SCAN_CH 49   // 1024*49 = 50176 >= N_NODES
__global__ __launch_bounds__(1024) void k_scan(const int* __restrict__ deg, int* __restrict__ rowptr) {
    __shared__ int wsum[16];
    const int tid = threadIdx.x;
    const int lane = tid & 63, wid = tid >> 6;
    const int base = tid * SCAN_CH;

    // phase 1: local sum of my chunk
    int lsum = 0;
    for (int i = 0; i < SCAN_CH; i++) {
        int idx = base + i;
        if (idx < N_NODES) lsum += deg[idx];
    }
    // wave inclusive scan (64 lanes)
    int incl = lsum;
#pragma unroll
    for (int off = 1; off < 64; off <<= 1) {
        int t = __shfl_up(incl, off);
        if (lane >= off) incl += t;
    }
    if (lane == 63) wsum[wid] = incl;
    __syncthreads();
    // wave 0 scans the 16 wave totals
    if (wid == 0 && lane < 16) {
        int v = wsum[lane];
#pragma unroll
        for (int off = 1; off < 16; off <<= 1) {
            int t = __shfl_up(v, off);
            if (lane >= off) v += t;
        }
        wsum[lane] = v;  // inclusive
    }
    __syncthreads();
    int waveoff = (wid == 0) ? 0 : wsum[wid - 1];
    int run = waveoff + incl - lsum;  // exclusive prefix at my chunk start

    // phase 2: writeback (re-read deg from L2)
    for (int i = 0; i < SCAN_CH; i++) {
        int idx = base + i;
        if (idx < N_NODES) {
            rowptr[idx] = run;
            run += deg[idx];
        }
    }
    if (tid == 1023) rowptr[N_NODES] = run;  // == total edges
}

// ---------------------------------------------------------------- CSR fill (edges bucketed by target)
__global__ void k_fill(const int* __restrict__ src, const int* __restrict__ tgt,
                       const int* __restrict__ rowptr, int* __restrict__ fill,
                       int* __restrict__ csr_src) {
    int e = blockIdx.x * blockDim.x + threadIdx.x;
    if (e >= N_EDGES) return;
    int d = tgt[e];
    int pos = atomicAdd(&fill[d], 1);
    csr_src[rowptr[d] + pos] = src[e];
}

// ---------------------------------------------------------------- gather-mean (atomic-free): 32 lanes per node, float4/lane
__global__ __launch_bounds__(256) void k_gather(const float* __restrict__ h,
                                                const int* __restrict__ csr_src,
                                                const int* __restrict__ rowptr,
                                                const float* __restrict__ dinv,
                                                float* __restrict__ agg) {
    int node = blockIdx.x * 8 + (threadIdx.x >> 5);
    if (node >= N_NODES) return;
    int lane = threadIdx.x & 31;
    int s = rowptr[node], e = rowptr[node + 1];
    float4 acc = {0.f, 0.f, 0.f, 0.f};
    int j = s;
    for (; j + 1 < e; j += 2) {               // 2-edge unroll for ILP
        int s0 = csr_src[j], s1 = csr_src[j + 1];
        float4 v0 = *(const float4*)(h + (size_t)s0 * C + lane * 4);
        float4 v1 = *(const float4*)(h + (size_t)s1 * C + lane * 4);
        acc.x += v0.x + v1.x; acc.y += v0.y + v1.y;
        acc.z += v0.z + v1.z; acc.w += v0.w + v1.w;
    }
    if (j < e) {
        int s0 = csr_src[j];
        float4 v0 = *(const float4*)(h + (size_t)s0 * C + lane * 4);
        acc.x += v0.x; acc.y += v0.y; acc.z += v0.z; acc.w += v0.w;
    }
    float sc = dinv[node];
    float4 o = {acc.x * sc, acc.y * sc, acc.z * sc, acc.w * sc};
    *(float4*)(agg + (size_t)node * C + lane * 4) = o;
}

// ---------------------------------------------------------------- fused SAGE layer GEMM
// out[m][n] = relu( agg[m] @ wl[n].T + hin[m] @ wr[n].T + bl[n] )   (agg pre-scaled by dinv)
#define GBM 64
#define GBK 32
__global__ __launch_bounds__(256) void k_sage_gemm(const float* __restrict__ agg,
                                                   const float* __restrict__ hin,
                                                   const float* __restrict__ wl,
                                                   const float* __restrict__ bl,
                                                   const float* __restrict__ wr,
                                                   float* __restrict__ hout) {
    __shared__ float As[GBK][GBM + 4];
    __shared__ float Bs[GBK][C + 4];
    const int tid = threadIdx.x;
    const int tx = tid & 31;   // cols tx*4 .. tx*4+3
    const int ty = tid >> 5;   // rows ty*8 .. ty*8+7
    const int m0 = blockIdx.x * GBM;

    float acc[8][4];
#pragma unroll
    for (int i = 0; i < 8; i++)
#pragma unroll
        for (int j = 0; j < 4; j++) acc[i][j] = 0.f;

    for (int k0 = 0; k0 < 256; k0 += GBK) {
        const bool isAgg = (k0 < 128);
        const float* Asrc = isAgg ? agg : hin;
        const float* W = isAgg ? wl : wr;
        const int ko = k0 & 127;
        __syncthreads();
#pragma unroll
        for (int i = 0; i < 2; i++) {
            int j = tid + i * 256;
            int m = j >> 3, kq = j & 7;
            int gm = m0 + m;
            int gmc = gm < N_NODES ? gm : N_NODES - 1;
            float4 v = *(const float4*)(Asrc + (size_t)gmc * C + ko + kq * 4);
            As[kq * 4 + 0][m] = v.x;
            As[kq * 4 + 1][m] = v.y;
            As[kq * 4 + 2][m] = v.z;
            As[kq * 4 + 3][m] = v.w;
        }
#pragma unroll
        for (int i = 0; i < 4; i++) {
            int j = tid + i * 256;
            int n = j >> 3, kq = j & 7;
            float4 v = *(const float4*)(W + n * C + ko + kq * 4);
            Bs[kq * 4 + 0][n] = v.x;
            Bs[kq * 4 + 1][n] = v.y;
            Bs[kq * 4 + 2][n] = v.z;
            Bs[kq * 4 + 3][n] = v.w;
        }
        __syncthreads();
#pragma unroll
        for (int kk = 0; kk < GBK; kk++) {
            float a[8], b[4];
            *(float4*)(a) = *(const float4*)&As[kk][ty * 8];
            *(float4*)(a + 4) = *(const float4*)&As[kk][ty * 8 + 4];
            *(float4*)(b) = *(const float4*)&Bs[kk][tx * 4];
#pragma unroll
            for (int im = 0; im < 8; im++)
#pragma unroll
                for (int in = 0; in < 4; in++)
                    acc[im][in] = fmaf(a[im], b[in], acc[im][in]);
        }
    }
    float4 bias = *(const float4*)(bl + tx * 4);
#pragma unroll
    for (int im = 0; im < 8; im++) {
        int gm = m0 + ty * 8 + im;
        if (gm < N_NODES) {
            float4 o;
            o.x = fmaxf(acc[im][0] + bias.x, 0.f);
            o.y = fmaxf(acc[im][1] + bias.y, 0.f);
            o.z = fmaxf(acc[im][2] + bias.z, 0.f);
            o.w = fmaxf(acc[im][3] + bias.w, 0.f);
            *(float4*)(hout + (size_t)gm * C + tx * 4) = o;
        }
    }
}

// ---------------------------------------------------------------- graph segment boundaries (batch is sorted)
__global__ void k_gstart(const int* __restrict__ batch, int* __restrict__ gstart) {
    int g = blockIdx.x * blockDim.x + threadIdx.x;
    if (g > N_GRAPHS) return;
    int lo = 0, hi = N_NODES;
    while (lo < hi) {
        int mid = (lo + hi) >> 1;
        if (batch[mid] < g) lo = mid + 1;
        else hi = mid;
    }
    gstart[g] = lo;
}

// ---------------------------------------------------------------- mean pool per graph
__global__ __launch_bounds__(512) void k_pool(const float* __restrict__ h,
                                              const int* __restrict__ gstart,
                                              float* __restrict__ gmean) {
    __shared__ float part[4][C];
    int g = blockIdx.x;
    int c = threadIdx.x & 127, p = threadIdx.x >> 7;
    int s = gstart[g], e = gstart[g + 1];
    float sum = 0.f;
    for (int n = s + p; n < e; n += 4) sum += h[(size_t)n * C + c];
    part[p][c] = sum;
    __syncthreads();
    if (p == 0) {
        float tot = part[0][c] + part[1][c] + part[2][c] + part[3][c];
        float cnt = fmaxf((float)(e - s), 1.0f);
        gmean[g * C + c] = tot / cnt;
    }
}

// ---------------------------------------------------------------- classifier head
__global__ __launch_bounds__(256) void k_final(const float* __restrict__ h,
                                               const float* __restrict__ gmean,
                                               const int* __restrict__ root,
                                               const float* __restrict__ wcls,
                                               const float* __restrict__ bcls,
                                               float* __restrict__ out) {
    __shared__ float red[8];
    int g = blockIdx.x, t = threadIdx.x;
    float v;
    if (t < 128) v = h[(size_t)root[g] * C + t];
    else v = gmean[g * C + (t - 128)];
    float p0 = v * wcls[t];
    float p1 = v * wcls[256 + t];
#pragma unroll
    for (int off = 32; off; off >>= 1) {
        p0 += __shfl_down(p0, off);
        p1 += __shfl_down(p1, off);
    }
    int wid = t >> 6;
    if ((t & 63) == 0) { red[wid] = p0; red[4 + wid] = p1; }
    __syncthreads();
    if (t == 0) {
        out[g * 2 + 0] = red[0] + red[1] + red[2] + red[3] + bcls[0];
        out[g * 2 + 1] = red[4] + red[5] + red[6] + red[7] + bcls[1];
    }
}

// ---------------------------------------------------------------- launch
extern "C" void kernel_launch(void* const* d_in, const int* in_sizes, int n_in,
                              void* d_out, int out_size, void* d_ws, size_t ws_size,
                              hipStream_t stream) {
    const float* x = (const float*)d_in[0];
    const int* ei = (const int*)d_in[1];
    const int* src = ei;
    const int* tgt = ei + N_EDGES;
    const int* root = (const int*)d_in[2];
    const int* batch = (const int*)d_in[3];
    const float* wl[4] = {(const float*)d_in[4], (const float*)d_in[7],
                          (const float*)d_in[10], (const float*)d_in[13]};
    const float* blv[4] = {(const float*)d_in[5], (const float*)d_in[8],
                           (const float*)d_in[11], (const float*)d_in[14]};
    const float* wr[4] = {(const float*)d_in[6], (const float*)d_in[9],
                          (const float*)d_in[12], (const float*)d_in[15]};
    const float* wcls = (const float*)d_in[16];
    const float* bcls = (const float*)d_in[17];
    float* out = (float*)d_out;

    // workspace carve-up (all 16B aligned)
    float* h = (float*)d_ws;                          // 50000*128 f
    float* agg = h + (size_t)N_NODES * C;             // 50000*128 f
    int* deg = (int*)(agg + (size_t)N_NODES * C);     // 50000 i
    float* dinv = (float*)(deg + N_NODES);            // 50000 f
    int* rowptr = (int*)(dinv + N_NODES);             // 50001 i
    int* fill = rowptr + N_NODES + 4;                 // 50000 i
    int* csr_src = fill + N_NODES;                    // 600000 i
    float* gmean = (float*)(csr_src + N_EDGES);       // 256*128 f
    int* gstart = (int*)(gmean + N_GRAPHS * C);       // 257 i

    hipMemsetAsync(deg, 0, N_NODES * sizeof(int), stream);
    hipMemsetAsync(fill, 0, N_NODES * sizeof(int), stream);
    k_deg<<<(N_EDGES + 255) / 256, 256, 0, stream>>>(tgt, deg);
    k_deginv<<<(N_NODES + 255) / 256, 256, 0, stream>>>(deg, dinv);
    k_scan<<<1, 1024, 0, stream>>>(deg, rowptr);
    k_fill<<<(N_EDGES + 255) / 256, 256, 0, stream>>>(src, tgt, rowptr, fill, csr_src);
    k_gstart<<<1, 512, 0, stream>>>(batch, gstart);

    const float* hin = x;
    for (int l = 0; l < 4; l++) {
        k_gather<<<(N_NODES + 7) / 8, 256, 0, stream>>>(hin, csr_src, rowptr, dinv, agg);
        k_sage_gemm<<<(N_NODES + GBM - 1) / GBM, 256, 0, stream>>>(
            agg, hin, wl[l], blv[l], wr[l], h);
        hin = h;
    }
    k_pool<<<N_GRAPHS, 512, 0, stream>>>(h, gstart, gmean);
    k_final<<<N_GRAPHS, 256, 0, stream>>>(h, gmean, root, wcls, bcls, out);
}

// Round 4
// 501.121 us; speedup vs baseline: 1.3452x; 1.3452x over previous
//
#include <hip/hip_runtime.h>
#include <hip/hip_bf16.h>

#define N_NODES 50000
#define N_EDGES 600000
#define N_GRAPHS 256
#define C 128
#define NB 196            // ceil(N_NODES/256) scan blocks

typedef unsigned short ushort;
typedef unsigned int uint;
typedef __attribute__((ext_vector_type(8))) short bfrag8;
typedef __attribute__((ext_vector_type(4))) float facc4;

// bf16 helpers (bit-level, RNE)
__device__ __forceinline__ ushort f2bf(float v) {
    uint u = __float_as_uint(v);
    u += 0x7FFFu + ((u >> 16) & 1u);
    return (ushort)(u >> 16);
}
__device__ __forceinline__ float bf2f(ushort u) {
    return __uint_as_float(((uint)u) << 16);
}
__device__ __forceinline__ void fsplit(float v, ushort& h, ushort& l) {
    h = f2bf(v);
    l = f2bf(v - bf2f(h));
}

// ---------------------------------------------------------------- degree histogram
__global__ void k_deg(const int* __restrict__ tgt, int* __restrict__ deg) {
    int e = blockIdx.x * blockDim.x + threadIdx.x;
    if (e < N_EDGES) atomicAdd(&deg[tgt[e]], 1);
}

// ---------------------------------------------------------------- scan stage 1: block sums (+ dinv fused)
__global__ __launch_bounds__(256) void k_bsum(const int* __restrict__ deg,
                                              int* __restrict__ bsum,
                                              float* __restrict__ dinv) {
    __shared__ int ws[4];
    int idx = blockIdx.x * 256 + threadIdx.x;
    int v = (idx < N_NODES) ? deg[idx] : 0;
    if (idx < N_NODES) dinv[idx] = 1.0f / fmaxf((float)v, 1.0f);
    int s = v;
#pragma unroll
    for (int off = 1; off < 64; off <<= 1) s += __shfl_xor(s, off);
    if ((threadIdx.x & 63) == 0) ws[threadIdx.x >> 6] = s;
    __syncthreads();
    if (threadIdx.x == 0) bsum[blockIdx.x] = ws[0] + ws[1] + ws[2] + ws[3];
}

// ---------------------------------------------------------------- scan stage 2: scan the 196 block sums
__global__ __launch_bounds__(256) void k_bscan(const int* __restrict__ bsum,
                                               int* __restrict__ boff,
                                               int* __restrict__ rowptr) {
    __shared__ int ws[4];
    int t = threadIdx.x, lane = t & 63, w = t >> 6;
    int v = (t < NB) ? bsum[t] : 0;
    int incl = v;
#pragma unroll
    for (int off = 1; off < 64; off <<= 1) {
        int u = __shfl_up(incl, off);
        if (lane >= off) incl += u;
    }
    if (lane == 63) ws[w] = incl;
    __syncthreads();
    int wo = 0;
    if (w > 0) wo += ws[0];
    if (w > 1) wo += ws[1];
    if (w > 2) wo += ws[2];
    if (t < NB) boff[t] = wo + incl - v;
    if (t == 0) rowptr[N_NODES] = N_EDGES;   // total is known a priori
}

// ---------------------------------------------------------------- scan stage 3: block-local scan + offset
__global__ __launch_bounds__(256) void k_rowptr(const int* __restrict__ deg,
                                                const int* __restrict__ boff,
                                                int* __restrict__ rowptr) {
    __shared__ int ws[4];
    int b = blockIdx.x, t = threadIdx.x;
    int idx = b * 256 + t;
    int lane = t & 63, w = t >> 6;
    int v = (idx < N_NODES) ? deg[idx] : 0;
    int incl = v;
#pragma unroll
    for (int off = 1; off < 64; off <<= 1) {
        int u = __shfl_up(incl, off);
        if (lane >= off) incl += u;
    }
    if (lane == 63) ws[w] = incl;
    __syncthreads();
    int wo = 0;
    if (w > 0) wo += ws[0];
    if (w > 1) wo += ws[1];
    if (w > 2) wo += ws[2];
    if (idx < N_NODES) rowptr[idx] = boff[b] + wo + incl - v;
}

// ---------------------------------------------------------------- CSR fill
__global__ void k_fill(const int* __restrict__ src, const int* __restrict__ tgt,
                       const int* __restrict__ rowptr, int* __restrict__ fill,
                       int* __restrict__ csr_src) {
    int e = blockIdx.x * blockDim.x + threadIdx.x;
    if (e >= N_EDGES) return;
    int d = tgt[e];
    int pos = atomicAdd(&fill[d], 1);
    csr_src[rowptr[d] + pos] = src[e];
}

// ---------------------------------------------------------------- x -> hi/lo planes (cols 128..255)
__global__ __launch_bounds__(256) void k_xsplit(const float* __restrict__ x,
                                                ushort* __restrict__ Ahi,
                                                ushort* __restrict__ Alo) {
    int gid = blockIdx.x * 256 + threadIdx.x;
    if (gid >= N_NODES * 32) return;
    int n = gid >> 5, c4 = (gid & 31) << 2;
    float4 v = *(const float4*)(x + (size_t)n * C + c4);
    ushort4 h, l;
    fsplit(v.x, h.x, l.x); fsplit(v.y, h.y, l.y);
    fsplit(v.z, h.z, l.z); fsplit(v.w, h.w, l.w);
    *(ushort4*)(Ahi + (size_t)n * 256 + 128 + c4) = h;
    *(ushort4*)(Alo + (size_t)n * 256 + 128 + c4) = l;
}

// ---------------------------------------------------------------- weights -> BT planes  BT[l][n][k] = k<128 ? wl[n][k] : wr[n][k-128]
struct WPtrs { const float* wl[4]; const float* wr[4]; };
__global__ __launch_bounds__(256) void k_wsplit(WPtrs wp, ushort* __restrict__ BTh,
                                                ushort* __restrict__ BTl) {
    int gid = blockIdx.x * 256 + threadIdx.x;   // 4*128*256 = 131072
    if (gid >= 4 * 128 * 256) return;
    int l = gid >> 15;
    int rem = gid & 32767;
    int n = rem >> 8, k = rem & 255;
    float v = (k < 128) ? wp.wl[l][n * 128 + k] : wp.wr[l][n * 128 + (k - 128)];
    ushort h, lo;
    fsplit(v, h, lo);
    BTh[gid] = h;
    BTl[gid] = lo;
}

// ---------------------------------------------------------------- gather-mean on planes
// reads cols 128..255 (h of prev layer, hi+lo), writes cols 0..127 (agg split)
__global__ __launch_bounds__(256) void k_gather(const ushort* __restrict__ Ahi_r,
                                                const ushort* __restrict__ Alo_r,
                                                ushort* __restrict__ Ahi_w,
                                                ushort* __restrict__ Alo_w,
                                                const int* __restrict__ csr_src,
                                                const int* __restrict__ rowptr,
                                                const float* __restrict__ dinv) {
    int node = blockIdx.x * 8 + (threadIdx.x >> 5);
    if (node >= N_NODES) return;
    int lane = threadIdx.x & 31;
    int c4 = lane << 2;
    int s = rowptr[node], e = rowptr[node + 1];
    float a0 = 0.f, a1 = 0.f, a2 = 0.f, a3 = 0.f;
    int j = s;
    for (; j + 1 < e; j += 2) {
        int s0 = csr_src[j], s1 = csr_src[j + 1];
        ushort4 h0 = *(const ushort4*)(Ahi_r + (size_t)s0 * 256 + 128 + c4);
        ushort4 l0 = *(const ushort4*)(Alo_r + (size_t)s0 * 256 + 128 + c4);
        ushort4 h1 = *(const ushort4*)(Ahi_r + (size_t)s1 * 256 + 128 + c4);
        ushort4 l1 = *(const ushort4*)(Alo_r + (size_t)s1 * 256 + 128 + c4);
        a0 += bf2f(h0.x) + bf2f(l0.x) + bf2f(h1.x) + bf2f(l1.x);
        a1 += bf2f(h0.y) + bf2f(l0.y) + bf2f(h1.y) + bf2f(l1.y);
        a2 += bf2f(h0.z) + bf2f(l0.z) + bf2f(h1.z) + bf2f(l1.z);
        a3 += bf2f(h0.w) + bf2f(l0.w) + bf2f(h1.w) + bf2f(l1.w);
    }
    if (j < e) {
        int s0 = csr_src[j];
        ushort4 h0 = *(const ushort4*)(Ahi_r + (size_t)s0 * 256 + 128 + c4);
        ushort4 l0 = *(const ushort4*)(Alo_r + (size_t)s0 * 256 + 128 + c4);
        a0 += bf2f(h0.x) + bf2f(l0.x);
        a1 += bf2f(h0.y) + bf2f(l0.y);
        a2 += bf2f(h0.z) + bf2f(l0.z);
        a3 += bf2f(h0.w) + bf2f(l0.w);
    }
    float sc = dinv[node];
    a0 *= sc; a1 *= sc; a2 *= sc; a3 *= sc;
    ushort4 h, l;
    fsplit(a0, h.x, l.x); fsplit(a1, h.y, l.y);
    fsplit(a2, h.z, l.z); fsplit(a3, h.w, l.w);
    *(ushort4*)(Ahi_w + (size_t)node * 256 + c4) = h;
    *(ushort4*)(Alo_w + (size_t)node * 256 + c4) = l;
}

// ---------------------------------------------------------------- split-bf16 MFMA GEMM
// D = Ahi·Bhi + Ahi·Blo + Alo·Bhi over K=256 (cols 0..127 agg, 128..255 h)
// block: 128 rows x 128 cols, 4 waves (2x2 of 64x64), 16x16x32 bf16 MFMA
__global__ __launch_bounds__(256, 2) void k_gemm(const ushort* __restrict__ Ahi,
                                                 const ushort* __restrict__ Alo,
                                                 const ushort* __restrict__ BTh,
                                                 const ushort* __restrict__ BTl,
                                                 const float* __restrict__ bl,
                                                 ushort* __restrict__ Hhi,
                                                 ushort* __restrict__ Hlo) {
    __shared__ short As[2][128][40];   // [plane][m][k], +8 pad
    __shared__ short Bs[2][128][40];   // [plane][n][k]
    const int tid = threadIdx.x;
    const int wave = tid >> 6, lane = tid & 63;
    const int m0 = blockIdx.x * 128;
    const int wm = (wave & 1) * 64;
    const int wn = (wave >> 1) * 64;
    const int l15 = lane & 15, lk = (lane >> 4) * 8;

    facc4 acc[4][4] = {};

    for (int k0 = 0; k0 < 256; k0 += 32) {
        __syncthreads();
        // stage A (both planes): 128 rows x 32 k = 512 x 16B per plane
#pragma unroll
        for (int i = 0; i < 2; i++) {
            int idx = tid * 2 + i;
            int r = idx >> 2, seg = (idx & 3) * 8;
            int gr = m0 + r; gr = gr < N_NODES ? gr : N_NODES - 1;
            bfrag8 vh = *(const bfrag8*)(Ahi + (size_t)gr * 256 + k0 + seg);
            bfrag8 vl = *(const bfrag8*)(Alo + (size_t)gr * 256 + k0 + seg);
            *(bfrag8*)&As[0][r][seg] = vh;
            *(bfrag8*)&As[1][r][seg] = vl;
            bfrag8 bh = *(const bfrag8*)(BTh + r * 256 + k0 + seg);
            bfrag8 bo = *(const bfrag8*)(BTl + r * 256 + k0 + seg);
            *(bfrag8*)&Bs[0][r][seg] = bh;
            *(bfrag8*)&Bs[1][r][seg] = bo;
        }
        __syncthreads();
        bfrag8 a[2][4], b[2][4];
#pragma unroll
        for (int t = 0; t < 4; t++) {
            a[0][t] = *(const bfrag8*)&As[0][wm + t * 16 + l15][lk];
            a[1][t] = *(const bfrag8*)&As[1][wm + t * 16 + l15][lk];
            b[0][t] = *(const bfrag8*)&Bs[0][wn + t * 16 + l15][lk];
            b[1][t] = *(const bfrag8*)&Bs[1][wn + t * 16 + l15][lk];
        }
#pragma unroll
        for (int mt = 0; mt < 4; mt++)
#pragma unroll
            for (int nt = 0; nt < 4; nt++) {
                acc[mt][nt] = __builtin_amdgcn_mfma_f32_16x16x32_bf16(a[0][mt], b[0][nt], acc[mt][nt], 0, 0, 0);
                acc[mt][nt] = __builtin_amdgcn_mfma_f32_16x16x32_bf16(a[0][mt], b[1][nt], acc[mt][nt], 0, 0, 0);
                acc[mt][nt] = __builtin_amdgcn_mfma_f32_16x16x32_bf16(a[1][mt], b[0][nt], acc[mt][nt], 0, 0, 0);
            }
    }
    // epilogue: bias + relu + split, write cols 128..255
    const int r4 = (lane >> 4) * 4;
#pragma unroll
    for (int mt = 0; mt < 4; mt++) {
#pragma unroll
        for (int nt = 0; nt < 4; nt++) {
            int col = wn + nt * 16 + l15;
            float bias = bl[col];
#pragma unroll
            for (int r = 0; r < 4; r++) {
                int grow = m0 + wm + mt * 16 + r4 + r;
                if (grow < N_NODES) {
                    float v = fmaxf(acc[mt][nt][r] + bias, 0.f);
                    ushort h, l;
                    fsplit(v, h, l);
                    Hhi[(size_t)grow * 256 + 128 + col] = h;
                    Hlo[(size_t)grow * 256 + 128 + col] = l;
                }
            }
        }
    }
}

// ---------------------------------------------------------------- graph segment boundaries
__global__ void k_gstart(const int* __restrict__ batch, int* __restrict__ gstart) {
    int g = blockIdx.x * blockDim.x + threadIdx.x;
    if (g > N_GRAPHS) return;
    int lo = 0, hi = N_NODES;
    while (lo < hi) {
        int mid = (lo + hi) >> 1;
        if (batch[mid] < g) lo = mid + 1;
        else hi = mid;
    }
    gstart[g] = lo;
}

// ---------------------------------------------------------------- mean pool per graph (reads planes)
__global__ __launch_bounds__(512) void k_pool(const ushort* __restrict__ Ahi,
                                              const ushort* __restrict__ Alo,
                                              const int* __restrict__ gstart,
                                              float* __restrict__ gmean) {
    __shared__ float part[4][C];
    int g = blockIdx.x;
    int c = threadIdx.x & 127, p = threadIdx.x >> 7;
    int s = gstart[g], e = gstart[g + 1];
    float sum = 0.f;
    for (int n = s + p; n < e; n += 4) {
        size_t o = (size_t)n * 256 + 128 + c;
        sum += bf2f(Ahi[o]) + bf2f(Alo[o]);
    }
    part[p][c] = sum;
    __syncthreads();
    if (p == 0) {
        float tot = part[0][c] + part[1][c] + part[2][c] + part[3][c];
        float cnt = fmaxf((float)(e - s), 1.0f);
        gmean[g * C + c] = tot / cnt;
    }
}

// ---------------------------------------------------------------- classifier head
__global__ __launch_bounds__(256) void k_final(const ushort* __restrict__ Ahi,
                                               const ushort* __restrict__ Alo,
                                               const float* __restrict__ gmean,
                                               const int* __restrict__ root,
                                               const float* __restrict__ wcls,
                                               const float* __restrict__ bcls,
                                               float* __restrict__ out) {
    __shared__ float red[8];
    int g = blockIdx.x, t = threadIdx.x;
    float v;
    if (t < 128) {
        size_t o = (size_t)root[g] * 256 + 128 + t;
        v = bf2f(Ahi[o]) + bf2f(Alo[o]);
    } else {
        v = gmean[g * C + (t - 128)];
    }
    float p0 = v * wcls[t];
    float p1 = v * wcls[256 + t];
#pragma unroll
    for (int off = 32; off; off >>= 1) {
        p0 += __shfl_down(p0, off);
        p1 += __shfl_down(p1, off);
    }
    int wid = t >> 6;
    if ((t & 63) == 0) { red[wid] = p0; red[4 + wid] = p1; }
    __syncthreads();
    if (t == 0) {
        out[g * 2 + 0] = red[0] + red[1] + red[2] + red[3] + bcls[0];
        out[g * 2 + 1] = red[4] + red[5] + red[6] + red[7] + bcls[1];
    }
}

// ---------------------------------------------------------------- launch
extern "C" void kernel_launch(void* const* d_in, const int* in_sizes, int n_in,
                              void* d_out, int out_size, void* d_ws, size_t ws_size,
                              hipStream_t stream) {
    const float* x = (const float*)d_in[0];
    const int* ei = (const int*)d_in[1];
    const int* src = ei;
    const int* tgt = ei + N_EDGES;
    const int* root = (const int*)d_in[2];
    const int* batch = (const int*)d_in[3];
    WPtrs wp;
    wp.wl[0] = (const float*)d_in[4];  wp.wr[0] = (const float*)d_in[6];
    wp.wl[1] = (const float*)d_in[7];  wp.wr[1] = (const float*)d_in[9];
    wp.wl[2] = (const float*)d_in[10]; wp.wr[2] = (const float*)d_in[12];
    wp.wl[3] = (const float*)d_in[13]; wp.wr[3] = (const float*)d_in[15];
    const float* blv[4] = {(const float*)d_in[5], (const float*)d_in[8],
                           (const float*)d_in[11], (const float*)d_in[14]};
    const float* wcls = (const float*)d_in[16];
    const float* bcls = (const float*)d_in[17];
    float* out = (float*)d_out;

    // workspace carve-up
    ushort* Ahi = (ushort*)d_ws;                      // 50000*256 bf16
    ushort* Alo = Ahi + (size_t)N_NODES * 256;        // 50000*256
    ushort* BTh = Alo + (size_t)N_NODES * 256;        // 4*128*256
    ushort* BTl = BTh + 4 * 128 * 256;                // 4*128*256
    int* deg = (int*)(BTl + 4 * 128 * 256);           // 50000
    float* dinv = (float*)(deg + N_NODES);            // 50000
    int* rowptr = (int*)(dinv + N_NODES);             // 50001
    int* fill = rowptr + N_NODES + 1;                 // 50000
    int* csr_src = fill + N_NODES;                    // 600000
    int* bsum = csr_src + N_EDGES;                    // 196
    int* boff = bsum + 256;                           // 196
    int* gstart = boff + 256;                         // 257
    float* gmean = (float*)(gstart + 260);            // 256*128

    hipMemsetAsync(deg, 0, N_NODES * sizeof(int), stream);
    hipMemsetAsync(fill, 0, N_NODES * sizeof(int), stream);
    k_deg<<<(N_EDGES + 255) / 256, 256, 0, stream>>>(tgt, deg);
    k_bsum<<<NB, 256, 0, stream>>>(deg, bsum, dinv);
    k_bscan<<<1, 256, 0, stream>>>(bsum, boff, rowptr);
    k_rowptr<<<NB, 256, 0, stream>>>(deg, boff, rowptr);
    k_fill<<<(N_EDGES + 255) / 256, 256, 0, stream>>>(src, tgt, rowptr, fill, csr_src);
    k_gstart<<<1, 512, 0, stream>>>(batch, gstart);
    k_xsplit<<<(N_NODES * 32 + 255) / 256, 256, 0, stream>>>(x, Ahi, Alo);
    k_wsplit<<<(4 * 128 * 256 + 255) / 256, 256, 0, stream>>>(wp, BTh, BTl);

    for (int l = 0; l < 4; l++) {
        k_gather<<<(N_NODES + 7) / 8, 256, 0, stream>>>(Ahi, Alo, Ahi, Alo,
                                                        csr_src, rowptr, dinv);
        k_gemm<<<(N_NODES + 127) / 128, 256, 0, stream>>>(
            Ahi, Alo, BTh + l * 32768, BTl + l * 32768, blv[l], Ahi, Alo);
    }
    k_pool<<<N_GRAPHS, 512, 0, stream>>>(Ahi, Alo, gstart, gmean);
    k_final<<<N_GRAPHS, 256, 0, stream>>>(Ahi, Alo, gmean, root, wcls, bcls, out);
}

// Round 5
// 486.363 us; speedup vs baseline: 1.3860x; 1.0303x over previous
//
#include <hip/hip_runtime.h>
#include <hip/hip_bf16.h>

#define N_NODES 50000
#define N_EDGES 600000
#define N_GRAPHS 256
#define C 128
#define NB 196            // ceil(N_NODES/256) scan blocks

typedef unsigned short ushort;
typedef unsigned int uint;
typedef __attribute__((ext_vector_type(8))) short bfrag8;
typedef __attribute__((ext_vector_type(4))) float facc4;

// bf16 helpers (bit-level, RNE)
__device__ __forceinline__ ushort f2bf(float v) {
    uint u = __float_as_uint(v);
    u += 0x7FFFu + ((u >> 16) & 1u);
    return (ushort)(u >> 16);
}
__device__ __forceinline__ float bf2f(ushort u) {
    return __uint_as_float(((uint)u) << 16);
}
__device__ __forceinline__ void fsplit(float v, ushort& h, ushort& l) {
    h = f2bf(v);
    l = f2bf(v - bf2f(h));
}

// ---------------------------------------------------------------- degree histogram
__global__ void k_deg(const int* __restrict__ tgt, int* __restrict__ deg) {
    int e = blockIdx.x * blockDim.x + threadIdx.x;
    if (e < N_EDGES) atomicAdd(&deg[tgt[e]], 1);
}

// ---------------------------------------------------------------- scan stage 1: block sums (+ dinv fused)
__global__ __launch_bounds__(256) void k_bsum(const int* __restrict__ deg,
                                              int* __restrict__ bsum,
                                              float* __restrict__ dinv) {
    __shared__ int ws[4];
    int idx = blockIdx.x * 256 + threadIdx.x;
    int v = (idx < N_NODES) ? deg[idx] : 0;
    if (idx < N_NODES) dinv[idx] = 1.0f / fmaxf((float)v, 1.0f);
    int s = v;
#pragma unroll
    for (int off = 1; off < 64; off <<= 1) s += __shfl_xor(s, off);
    if ((threadIdx.x & 63) == 0) ws[threadIdx.x >> 6] = s;
    __syncthreads();
    if (threadIdx.x == 0) bsum[blockIdx.x] = ws[0] + ws[1] + ws[2] + ws[3];
}

// ---------------------------------------------------------------- scan stage 2: scan the 196 block sums
__global__ __launch_bounds__(256) void k_bscan(const int* __restrict__ bsum,
                                               int* __restrict__ boff,
                                               int* __restrict__ rowptr) {
    __shared__ int ws[4];
    int t = threadIdx.x, lane = t & 63, w = t >> 6;
    int v = (t < NB) ? bsum[t] : 0;
    int incl = v;
#pragma unroll
    for (int off = 1; off < 64; off <<= 1) {
        int u = __shfl_up(incl, off);
        if (lane >= off) incl += u;
    }
    if (lane == 63) ws[w] = incl;
    __syncthreads();
    int wo = 0;
    if (w > 0) wo += ws[0];
    if (w > 1) wo += ws[1];
    if (w > 2) wo += ws[2];
    if (t < NB) boff[t] = wo + incl - v;
    if (t == 0) rowptr[N_NODES] = N_EDGES;   // total is known a priori
}

// ---------------------------------------------------------------- scan stage 3: block-local scan + offset
__global__ __launch_bounds__(256) void k_rowptr(const int* __restrict__ deg,
                                                const int* __restrict__ boff,
                                                int* __restrict__ rowptr) {
    __shared__ int ws[4];
    int b = blockIdx.x, t = threadIdx.x;
    int idx = b * 256 + t;
    int lane = t & 63, w = t >> 6;
    int v = (idx < N_NODES) ? deg[idx] : 0;
    int incl = v;
#pragma unroll
    for (int off = 1; off < 64; off <<= 1) {
        int u = __shfl_up(incl, off);
        if (lane >= off) incl += u;
    }
    if (lane == 63) ws[w] = incl;
    __syncthreads();
    int wo = 0;
    if (w > 0) wo += ws[0];
    if (w > 1) wo += ws[1];
    if (w > 2) wo += ws[2];
    if (idx < N_NODES) rowptr[idx] = boff[b] + wo + incl - v;
}

// ---------------------------------------------------------------- CSR fill
__global__ void k_fill(const int* __restrict__ src, const int* __restrict__ tgt,
                       const int* __restrict__ rowptr, int* __restrict__ fill,
                       int* __restrict__ csr_src) {
    int e = blockIdx.x * blockDim.x + threadIdx.x;
    if (e >= N_EDGES) return;
    int d = tgt[e];
    int pos = atomicAdd(&fill[d], 1);
    csr_src[rowptr[d] + pos] = src[e];
}

// ---------------------------------------------------------------- x -> hi/lo planes (cols 128..255)
__global__ __launch_bounds__(256) void k_xsplit(const float* __restrict__ x,
                                                ushort* __restrict__ Ahi,
                                                ushort* __restrict__ Alo) {
    int gid = blockIdx.x * 256 + threadIdx.x;
    if (gid >= N_NODES * 32) return;
    int n = gid >> 5, c4 = (gid & 31) << 2;
    float4 v = *(const float4*)(x + (size_t)n * C + c4);
    ushort4 h, l;
    fsplit(v.x, h.x, l.x); fsplit(v.y, h.y, l.y);
    fsplit(v.z, h.z, l.z); fsplit(v.w, h.w, l.w);
    *(ushort4*)(Ahi + (size_t)n * 256 + 128 + c4) = h;
    *(ushort4*)(Alo + (size_t)n * 256 + 128 + c4) = l;
}

// ---------------------------------------------------------------- weights -> BT planes  BT[l][n][k] = k<128 ? wl[n][k] : wr[n][k-128]
struct WPtrs { const float* wl[4]; const float* wr[4]; };
__global__ __launch_bounds__(256) void k_wsplit(WPtrs wp, ushort* __restrict__ BTh,
                                                ushort* __restrict__ BTl) {
    int gid = blockIdx.x * 256 + threadIdx.x;   // 4*128*256 = 131072
    if (gid >= 4 * 128 * 256) return;
    int l = gid >> 15;
    int rem = gid & 32767;
    int n = rem >> 8, k = rem & 255;
    float v = (k < 128) ? wp.wl[l][n * 128 + k] : wp.wr[l][n * 128 + (k - 128)];
    ushort h, lo;
    fsplit(v, h, lo);
    BTh[gid] = h;
    BTl[gid] = lo;
}

// ---------------------------------------------------------------- gather-mean on planes
// reads cols 128..255 (h of prev layer, hi+lo), writes cols 0..127 (agg split)
// 32 lanes per node; 4-edge unroll -> 8 feature loads in flight per half-wave
__global__ __launch_bounds__(256) void k_gather(const ushort* __restrict__ Ahi_r,
                                                const ushort* __restrict__ Alo_r,
                                                ushort* __restrict__ Ahi_w,
                                                ushort* __restrict__ Alo_w,
                                                const int* __restrict__ csr_src,
                                                const int* __restrict__ rowptr,
                                                const float* __restrict__ dinv) {
    int node = blockIdx.x * 8 + (threadIdx.x >> 5);
    if (node >= N_NODES) return;
    int lane = threadIdx.x & 31;
    int c4 = lane << 2;
    int s = rowptr[node], e = rowptr[node + 1];
    float a0 = 0.f, a1 = 0.f, a2 = 0.f, a3 = 0.f;
    int j = s;
    for (; j + 3 < e; j += 4) {
        int s0 = csr_src[j], s1 = csr_src[j + 1];
        int s2 = csr_src[j + 2], s3 = csr_src[j + 3];
        ushort4 h0 = *(const ushort4*)(Ahi_r + (size_t)s0 * 256 + 128 + c4);
        ushort4 l0 = *(const ushort4*)(Alo_r + (size_t)s0 * 256 + 128 + c4);
        ushort4 h1 = *(const ushort4*)(Ahi_r + (size_t)s1 * 256 + 128 + c4);
        ushort4 l1 = *(const ushort4*)(Alo_r + (size_t)s1 * 256 + 128 + c4);
        ushort4 h2 = *(const ushort4*)(Ahi_r + (size_t)s2 * 256 + 128 + c4);
        ushort4 l2 = *(const ushort4*)(Alo_r + (size_t)s2 * 256 + 128 + c4);
        ushort4 h3 = *(const ushort4*)(Ahi_r + (size_t)s3 * 256 + 128 + c4);
        ushort4 l3 = *(const ushort4*)(Alo_r + (size_t)s3 * 256 + 128 + c4);
        a0 += (bf2f(h0.x) + bf2f(l0.x)) + (bf2f(h1.x) + bf2f(l1.x))
            + (bf2f(h2.x) + bf2f(l2.x)) + (bf2f(h3.x) + bf2f(l3.x));
        a1 += (bf2f(h0.y) + bf2f(l0.y)) + (bf2f(h1.y) + bf2f(l1.y))
            + (bf2f(h2.y) + bf2f(l2.y)) + (bf2f(h3.y) + bf2f(l3.y));
        a2 += (bf2f(h0.z) + bf2f(l0.z)) + (bf2f(h1.z) + bf2f(l1.z))
            + (bf2f(h2.z) + bf2f(l2.z)) + (bf2f(h3.z) + bf2f(l3.z));
        a3 += (bf2f(h0.w) + bf2f(l0.w)) + (bf2f(h1.w) + bf2f(l1.w))
            + (bf2f(h2.w) + bf2f(l2.w)) + (bf2f(h3.w) + bf2f(l3.w));
    }
    for (; j < e; j++) {
        int s0 = csr_src[j];
        ushort4 h0 = *(const ushort4*)(Ahi_r + (size_t)s0 * 256 + 128 + c4);
        ushort4 l0 = *(const ushort4*)(Alo_r + (size_t)s0 * 256 + 128 + c4);
        a0 += bf2f(h0.x) + bf2f(l0.x);
        a1 += bf2f(h0.y) + bf2f(l0.y);
        a2 += bf2f(h0.z) + bf2f(l0.z);
        a3 += bf2f(h0.w) + bf2f(l0.w);
    }
    float sc = dinv[node];
    a0 *= sc; a1 *= sc; a2 *= sc; a3 *= sc;
    ushort4 h, l;
    fsplit(a0, h.x, l.x); fsplit(a1, h.y, l.y);
    fsplit(a2, h.z, l.z); fsplit(a3, h.w, l.w);
    *(ushort4*)(Ahi_w + (size_t)node * 256 + c4) = h;
    *(ushort4*)(Alo_w + (size_t)node * 256 + c4) = l;
}

// ---------------------------------------------------------------- split-bf16 MFMA GEMM, software-pipelined staging
// D = Ahi·Bhi + Ahi·Blo + Alo·Bhi over K=256 (cols 0..127 agg, 128..255 h)
// block: 128x128, 4 waves (2x2 of 64x64), 16x16x32 bf16 MFMA.
// K-step s+1's global loads are issued right after the barrier and consumed
// (vmcnt-waited) only at step s+1's LDS writes -> global latency hides under MFMA.
__global__ __launch_bounds__(256) void k_gemm(const ushort* __restrict__ Ahi,
                                              const ushort* __restrict__ Alo,
                                              const ushort* __restrict__ BTh,
                                              const ushort* __restrict__ BTl,
                                              const float* __restrict__ bl,
                                              ushort* __restrict__ Hhi,
                                              ushort* __restrict__ Hlo) {
    __shared__ short As[2][128][40];   // [plane][m][k], pad to 40 (conflict-free-ish reads)
    __shared__ short Bs[2][128][40];   // [plane][n][k]
    const int tid = threadIdx.x;
    const int wave = tid >> 6, lane = tid & 63;
    const int m0 = blockIdx.x * 128;
    const int wm = (wave & 1) * 64;
    const int wn = (wave >> 1) * 64;
    const int l15 = lane & 15, lk = (lane >> 4) * 8;

    // staging coords: thread -> row sr, 16-short segment sc
    const int sr = tid >> 1;
    const int sc = (tid & 1) * 16;
    int garow = m0 + sr; if (garow >= N_NODES) garow = N_NODES - 1;
    const ushort* pAh = Ahi + (size_t)garow * 256 + sc;
    const ushort* pAl = Alo + (size_t)garow * 256 + sc;
    const ushort* pBh = BTh + sr * 256 + sc;
    const ushort* pBl = BTl + sr * 256 + sc;

    bfrag8 rAh0, rAh1, rAl0, rAl1, rBh0, rBh1, rBl0, rBl1;
#define LOADSTEP(K0) do { \
        rAh0 = *(const bfrag8*)(pAh + (K0));     rAh1 = *(const bfrag8*)(pAh + (K0) + 8); \
        rAl0 = *(const bfrag8*)(pAl + (K0));     rAl1 = *(const bfrag8*)(pAl + (K0) + 8); \
        rBh0 = *(const bfrag8*)(pBh + (K0));     rBh1 = *(const bfrag8*)(pBh + (K0) + 8); \
        rBl0 = *(const bfrag8*)(pBl + (K0));     rBl1 = *(const bfrag8*)(pBl + (K0) + 8); \
    } while (0)

    LOADSTEP(0);
    facc4 acc[4][4] = {};
#pragma unroll
    for (int s = 0; s < 8; s++) {
        *(bfrag8*)&As[0][sr][sc]     = rAh0;  *(bfrag8*)&As[0][sr][sc + 8] = rAh1;
        *(bfrag8*)&As[1][sr][sc]     = rAl0;  *(bfrag8*)&As[1][sr][sc + 8] = rAl1;
        *(bfrag8*)&Bs[0][sr][sc]     = rBh0;  *(bfrag8*)&Bs[0][sr][sc + 8] = rBh1;
        *(bfrag8*)&Bs[1][sr][sc]     = rBl0;  *(bfrag8*)&Bs[1][sr][sc + 8] = rBl1;
        __syncthreads();
        if (s < 7) LOADSTEP((s + 1) * 32);   // prefetch next K-step (overlaps MFMAs below)
        bfrag8 a[2][4], b[2][4];
#pragma unroll
        for (int t = 0; t < 4; t++) {
            a[0][t] = *(const bfrag8*)&As[0][wm + t * 16 + l15][lk];
            a[1][t] = *(const bfrag8*)&As[1][wm + t * 16 + l15][lk];
            b[0][t] = *(const bfrag8*)&Bs[0][wn + t * 16 + l15][lk];
            b[1][t] = *(const bfrag8*)&Bs[1][wn + t * 16 + l15][lk];
        }
#pragma unroll
        for (int mt = 0; mt < 4; mt++)
#pragma unroll
            for (int nt = 0; nt < 4; nt++) {
                acc[mt][nt] = __builtin_amdgcn_mfma_f32_16x16x32_bf16(a[0][mt], b[0][nt], acc[mt][nt], 0, 0, 0);
                acc[mt][nt] = __builtin_amdgcn_mfma_f32_16x16x32_bf16(a[0][mt], b[1][nt], acc[mt][nt], 0, 0, 0);
                acc[mt][nt] = __builtin_amdgcn_mfma_f32_16x16x32_bf16(a[1][mt], b[0][nt], acc[mt][nt], 0, 0, 0);
            }
        __syncthreads();
    }
#undef LOADSTEP

    // epilogue: bias + relu + split, write cols 128..255
    const int r4 = (lane >> 4) * 4;
#pragma unroll
    for (int mt = 0; mt < 4; mt++) {
#pragma unroll
        for (int nt = 0; nt < 4; nt++) {
            int col = wn + nt * 16 + l15;
            float bias = bl[col];
#pragma unroll
            for (int r = 0; r < 4; r++) {
                int grow = m0 + wm + mt * 16 + r4 + r;
                if (grow < N_NODES) {
                    float v = fmaxf(acc[mt][nt][r] + bias, 0.f);
                    ushort h, l;
                    fsplit(v, h, l);
                    Hhi[(size_t)grow * 256 + 128 + col] = h;
                    Hlo[(size_t)grow * 256 + 128 + col] = l;
                }
            }
        }
    }
}

// ---------------------------------------------------------------- graph segment boundaries
__global__ void k_gstart(const int* __restrict__ batch, int* __restrict__ gstart) {
    int g = blockIdx.x * blockDim.x + threadIdx.x;
    if (g > N_GRAPHS) return;
    int lo = 0, hi = N_NODES;
    while (lo < hi) {
        int mid = (lo + hi) >> 1;
        if (batch[mid] < g) lo = mid + 1;
        else hi = mid;
    }
    gstart[g] = lo;
}

// ---------------------------------------------------------------- mean pool per graph (reads planes)
__global__ __launch_bounds__(512) void k_pool(const ushort* __restrict__ Ahi,
                                              const ushort* __restrict__ Alo,
                                              const int* __restrict__ gstart,
                                              float* __restrict__ gmean) {
    __shared__ float part[4][C];
    int g = blockIdx.x;
    int c = threadIdx.x & 127, p = threadIdx.x >> 7;
    int s = gstart[g], e = gstart[g + 1];
    float sum = 0.f;
    for (int n = s + p; n < e; n += 4) {
        size_t o = (size_t)n * 256 + 128 + c;
        sum += bf2f(Ahi[o]) + bf2f(Alo[o]);
    }
    part[p][c] = sum;
    __syncthreads();
    if (p == 0) {
        float tot = part[0][c] + part[1][c] + part[2][c] + part[3][c];
        float cnt = fmaxf((float)(e - s), 1.0f);
        gmean[g * C + c] = tot / cnt;
    }
}

// ---------------------------------------------------------------- classifier head
__global__ __launch_bounds__(256) void k_final(const ushort* __restrict__ Ahi,
                                               const ushort* __restrict__ Alo,
                                               const float* __restrict__ gmean,
                                               const int* __restrict__ root,
                                               const float* __restrict__ wcls,
                                               const float* __restrict__ bcls,
                                               float* __restrict__ out) {
    __shared__ float red[8];
    int g = blockIdx.x, t = threadIdx.x;
    float v;
    if (t < 128) {
        size_t o = (size_t)root[g] * 256 + 128 + t;
        v = bf2f(Ahi[o]) + bf2f(Alo[o]);
    } else {
        v = gmean[g * C + (t - 128)];
    }
    float p0 = v * wcls[t];
    float p1 = v * wcls[256 + t];
#pragma unroll
    for (int off = 32; off; off >>= 1) {
        p0 += __shfl_down(p0, off);
        p1 += __shfl_down(p1, off);
    }
    int wid = t >> 6;
    if ((t & 63) == 0) { red[wid] = p0; red[4 + wid] = p1; }
    __syncthreads();
    if (t == 0) {
        out[g * 2 + 0] = red[0] + red[1] + red[2] + red[3] + bcls[0];
        out[g * 2 + 1] = red[4] + red[5] + red[6] + red[7] + bcls[1];
    }
}

// ---------------------------------------------------------------- launch
extern "C" void kernel_launch(void* const* d_in, const int* in_sizes, int n_in,
                              void* d_out, int out_size, void* d_ws, size_t ws_size,
                              hipStream_t stream) {
    const float* x = (const float*)d_in[0];
    const int* ei = (const int*)d_in[1];
    const int* src = ei;
    const int* tgt = ei + N_EDGES;
    const int* root = (const int*)d_in[2];
    const int* batch = (const int*)d_in[3];
    WPtrs wp;
    wp.wl[0] = (const float*)d_in[4];  wp.wr[0] = (const float*)d_in[6];
    wp.wl[1] = (const float*)d_in[7];  wp.wr[1] = (const float*)d_in[9];
    wp.wl[2] = (const float*)d_in[10]; wp.wr[2] = (const float*)d_in[12];
    wp.wl[3] = (const float*)d_in[13]; wp.wr[3] = (const float*)d_in[15];
    const float* blv[4] = {(const float*)d_in[5], (const float*)d_in[8],
                           (const float*)d_in[11], (const float*)d_in[14]};
    const float* wcls = (const float*)d_in[16];
    const float* bcls = (const float*)d_in[17];
    float* out = (float*)d_out;

    // workspace carve-up
    ushort* Ahi = (ushort*)d_ws;                      // 50000*256 bf16
    ushort* Alo = Ahi + (size_t)N_NODES * 256;        // 50000*256
    ushort* BTh = Alo + (size_t)N_NODES * 256;        // 4*128*256
    ushort* BTl = BTh + 4 * 128 * 256;                // 4*128*256
    int* deg = (int*)(BTl + 4 * 128 * 256);           // 50000
    float* dinv = (float*)(deg + N_NODES);            // 50000
    int* rowptr = (int*)(dinv + N_NODES);             // 50001
    int* fill = rowptr + N_NODES + 1;                 // 50000
    int* csr_src = fill + N_NODES;                    // 600000
    int* bsum = csr_src + N_EDGES;                    // 196
    int* boff = bsum + 256;                           // 196
    int* gstart = boff + 256;                         // 257
    float* gmean = (float*)(gstart + 260);            // 256*128

    hipMemsetAsync(deg, 0, N_NODES * sizeof(int), stream);
    hipMemsetAsync(fill, 0, N_NODES * sizeof(int), stream);
    k_deg<<<(N_EDGES + 255) / 256, 256, 0, stream>>>(tgt, deg);
    k_bsum<<<NB, 256, 0, stream>>>(deg, bsum, dinv);
    k_bscan<<<1, 256, 0, stream>>>(bsum, boff, rowptr);
    k_rowptr<<<NB, 256, 0, stream>>>(deg, boff, rowptr);
    k_fill<<<(N_EDGES + 255) / 256, 256, 0, stream>>>(src, tgt, rowptr, fill, csr_src);
    k_gstart<<<1, 512, 0, stream>>>(batch, gstart);
    k_xsplit<<<(N_NODES * 32 + 255) / 256, 256, 0, stream>>>(x, Ahi, Alo);
    k_wsplit<<<(4 * 128 * 256 + 255) / 256, 256, 0, stream>>>(wp, BTh, BTl);

    for (int l = 0; l < 4; l++) {
        k_gather<<<(N_NODES + 7) / 8, 256, 0, stream>>>(Ahi, Alo, Ahi, Alo,
                                                        csr_src, rowptr, dinv);
        k_gemm<<<(N_NODES + 127) / 128, 256, 0, stream>>>(
            Ahi, Alo, BTh + l * 32768, BTl + l * 32768, blv[l], Ahi, Alo);
    }
    k_pool<<<N_GRAPHS, 512, 0, stream>>>(Ahi, Alo, gstart, gmean);
    k_final<<<N_GRAPHS, 256, 0, stream>>>(Ahi, Alo, gmean, root, wcls, bcls, out);
}